// Round 4
// baseline (479.626 us; speedup 1.0000x reference)
//
#include <hip/hip_runtime.h>
#include <stdint.h>
#include <stddef.h>

#define NROWS 8192
#define NCOLS 8192       // K dimension = noise-matrix column count
#define DDIM  1024

typedef float  f32x4 __attribute__((ext_vector_type(4)));
typedef _Float16 f16x8 __attribute__((ext_vector_type(8)));

#if __has_builtin(__builtin_amdgcn_exp2f)
#define EXP2F(x) __builtin_amdgcn_exp2f(x)
#else
#define EXP2F(x) exp2f(x)
#endif
#if __has_builtin(__builtin_amdgcn_logf)
#define LOG2F(x) __builtin_amdgcn_logf(x)     // v_log_f32 = log2
#else
#define LOG2F(x) log2f(x)
#endif
#if __has_builtin(__builtin_amdgcn_sqrtf)
#define SQRTF(x) __builtin_amdgcn_sqrtf(x)
#else
#define SQRTF(x) sqrtf(x)
#endif

// ---------------- Threefry-2x32, key = (0, 42) (jax.random.key(42)) ---------
__device__ __forceinline__ uint32_t rotl32(uint32_t x, uint32_t r){
  return (x << r) | (x >> (32u - r));
}

__device__ __forceinline__ void threefry2x32(uint32_t x0, uint32_t x1,
                                             uint32_t& o0, uint32_t& o1){
  const uint32_t k0 = 0u, k1 = 42u;
  const uint32_t k2 = k0 ^ k1 ^ 0x1BD11BDAu;
  x0 += k0; x1 += k1;
#define TF_R(r) { x0 += x1; x1 = rotl32(x1, r); x1 ^= x0; }
  TF_R(13) TF_R(15) TF_R(26) TF_R(6)
  x0 += k1; x1 += k2 + 1u;
  TF_R(17) TF_R(29) TF_R(16) TF_R(24)
  x0 += k2; x1 += k0 + 2u;
  TF_R(13) TF_R(15) TF_R(26) TF_R(6)
  x0 += k0; x1 += k1 + 3u;
  TF_R(17) TF_R(29) TF_R(16) TF_R(24)
  x0 += k1; x1 += k2 + 4u;
  TF_R(13) TF_R(15) TF_R(26) TF_R(6)
  x0 += k2; x1 += k0 + 5u;
#undef TF_R
  o0 = x0; o1 = x1;
}

// Partitionable-threefry element: flat index f -> E' = exp(2*normal)*2^-4.
__device__ __forceinline__ float elemE(uint32_t f){
  uint32_t o0, o1;
  threefry2x32(0u, f, o0, o1);
  const uint32_t b = o0 ^ o1;
  float u = __uint_as_float((b >> 9) | 0x3F800000u) - 1.0f;   // [0,1)
  const float lo = -0.99999994f;                              // nextafter(-1,0)
  float v = fmaf(u, 2.0f, lo);
  v = fmaxf(v, lo);
  const float t1 = fmaf(-v, v, 1.0f);                         // 1 - v^2
  float w = LOG2F(t1) * (-0.69314718f);                       // -ln(1-v^2)
  float p;
  if (w < 5.0f){
    w -= 2.5f;
    p =              3.97426473e-08f;
    p = fmaf(p, w,   4.85465e-07f);
    p = fmaf(p, w,  -4.98283e-06f);
    p = fmaf(p, w,  -6.21053e-06f);
    p = fmaf(p, w,   3.09120e-04f);
    p = fmaf(p, w,  -1.77290e-03f);
    p = fmaf(p, w,  -5.90817e-03f);
    p = fmaf(p, w,   3.48803163e-01f);
    p = fmaf(p, w,   2.12331355e+00f);
  } else {
    w = SQRTF(w) - 3.0f;
    p =             -2.83147363e-04f;
    p = fmaf(p, w,   1.42765560e-04f);
    p = fmaf(p, w,   1.90825981e-03f);
    p = fmaf(p, w,  -5.19500608e-03f);
    p = fmaf(p, w,   8.11688602e-03f);
    p = fmaf(p, w,  -1.07798386e-02f);
    p = fmaf(p, w,   1.33487061e-02f);
    p = fmaf(p, w,   1.41658096e+00f);
    p = fmaf(p, w,   4.00643396e+00f);
  }
  const float m = p * v;                         // sqrt(2)*erfinv(v) ~ N(0,1)
  return EXP2F(fmaf(m, 2.8853900817779268f, -4.0f)); // exp(2m)*2^-4
}

__device__ __forceinline__ uint16_t f2h(float a){
  union { _Float16 h; uint16_t u; } c; c.h = (_Float16)a; return c.u;
}

// ---------------- transpose: x [8192][1024] f32 -> xT f16 -------------------
__global__ __launch_bounds__(256) void transpose_cast(const float* __restrict__ x,
                                                      uint16_t* __restrict__ xT){
  __shared__ float tile[32][33];
  const int tx = threadIdx.x & 31;
  const int ty = threadIdx.x >> 5;          // 0..7
  const int dcol = blockIdx.x * 32;
  const int nrow = blockIdx.y * 32;
  #pragma unroll
  for (int r = 0; r < 32; r += 8)
    tile[ty + r][tx] = x[(size_t)(nrow + ty + r) * DDIM + dcol + tx];
  __syncthreads();
  #pragma unroll
  for (int r = 0; r < 32; r += 8)
    xT[(size_t)(dcol + ty + r) * NROWS + nrow + tx] = f2h(tile[tx][ty + r]);
}

typedef const __attribute__((address_space(1))) void GAS;
typedef __attribute__((address_space(3))) void LAS;

__device__ __forceinline__ void gload16(const void* g, void* l){
  __builtin_amdgcn_global_load_lds((GAS*)g, (LAS*)l, 16, 0, 0);
}

// ============= fused generate-in-GEMM kernel (no P materialization) =========
// Grid = 256 blocks x 512 threads, 1 block/CU (135 KB LDS). Block b owns
// output rows [32b, 32b+32) x ALL 1024 cols. Streams K in steps of 32:
// per step, the block GENERATES its 32x32 A-tile (P values, counter-based
// threefry -> computable anywhere) into LDS and stages the 1024x32 xT K-slice
// via global_load_lds. Every P element is generated exactly once; P never
// touches memory. Row sums accumulate during generation (softmax denom).
// No inter-block communication of any kind.
//
// LDS map (uint16 elems): Bs0 @0 (32768) | Bs1 @32768 | As0 @65536 (1024) |
// As1 @66560 | total 67584 elems = 135168 B. Ssum reuses Bs0 after the loop.
// A/B rows are 64 B (32 f16): 16B-granule g of row r stored at phys g^(r&3)
// (4-way spread; b128 reads land 2-way(A)/4-way(B) conflicts - acceptable).
#define FM2 32
#define FK2 32
#define NST (NCOLS / FK2)    // 256 K-steps
#define LB0 0
#define LB1 32768
#define LA0 65536
#define LA1 66560
#define LDS_ELEMS 67584

__global__ __launch_bounds__(512, 2) void fused32(
    const uint16_t* __restrict__ xT,   // [1024][8192] f16
    float* __restrict__ O)             // [8192][1024] f32
{
  extern __shared__ uint16_t sm[];

  const int t = threadIdx.x;
  const size_t m0 = (size_t)blockIdx.x * FM2;

  const int lane = t & 63;
  const int w    = t >> 6;             // 0..7 waves: 2m x 4n
  const int wr   = (w >> 2) * 16;      // 0 or 16
  const int wn0  = (w & 3) * 256;      // n-range base
  const int l15  = lane & 15;
  const int lq   = lane >> 4;          // 0..3
  const int kb   = (lq ^ (l15 & 3)) * 8;   // frag phys k-granule (elems)

  // --- gen mapping: thread t -> local row t>>4, cols 2*(t&15)+{0,1} per step
  const int grow = t >> 4;             // 0..31
  const int gq   = t & 15;
  const uint32_t genbase = (uint32_t)(m0 + (size_t)grow) * 8192u + (uint32_t)(gq * 2);
  const int aoff = grow * FK2 + (((gq >> 2) ^ (grow & 3)) * 8) + (gq & 3) * 2;

  // --- B staging: 1024x32 slice = 4096 granules; thread t covers granules
  // t+512r: d = (t>>2)+128r, phys slot t&3 holds logical (t&3)^(d&3).
  const int srow = t >> 2;             // 0..127
  const int sg   = (t & 3) ^ (srow & 3);
  const uint16_t* gB = xT + (size_t)srow * NCOLS + sg * 8;

  float myS = 0.0f;
  f32x4 acc[16];
  #pragma unroll
  for (int n = 0; n < 16; ++n)
    #pragma unroll
    for (int r = 0; r < 4; ++r) acc[n][r] = 0.0f;

  auto STAGEB = [&](int lb, int s){
    const int k0 = s * FK2;
    #pragma unroll
    for (int r = 0; r < 8; ++r)
      gload16(gB + (size_t)(128 * r) * NCOLS + k0, sm + lb + (t + 512 * r) * 8);
  };
  auto GENA = [&](int la, int s){
    const uint32_t f0 = genbase + (uint32_t)(s * FK2);
    float e0 = elemE(f0);
    float e1 = elemE(f0 + 1u);
    myS += e0 + e1;
    union { _Float16 h[2]; uint32_t u; } pk;
    pk.h[0] = (_Float16)e0; pk.h[1] = (_Float16)e1;
    *reinterpret_cast<uint32_t*>(sm + la + aoff) = pk.u;  // ds_write_b32
  };

  // one {ds-frag-read + MFMA} + {stage/gen next} phase; single barrier/step
  auto STEP = [&](int lb, int la, int lb2, int la2, int s){
    if (s + 1 < NST){
      STAGEB(lb2, s + 1);              // -> other B buffer (in flight)
      GENA(la2, s + 1);                // VALU bulk, overlaps everything
    }
    const f16x8 af = *reinterpret_cast<const f16x8*>(sm + la + (wr + l15) * FK2 + kb);
    __builtin_amdgcn_s_setprio(1);
    #pragma unroll
    for (int n = 0; n < 16; ++n){
      const f16x8 bf = *reinterpret_cast<const f16x8*>(sm + lb + (wn0 + n * 16 + l15) * FK2 + kb);
      acc[n] = __builtin_amdgcn_mfma_f32_16x16x32_f16(af, bf, acc[n], 0, 0, 0);
    }
    __builtin_amdgcn_s_setprio(0);
    // drain: my frag reads + A writes (lgkm), my B-stage loads (vm) -- loads
    // were issued ~500 VALU insts ago, so this is cheap; then barrier.
    asm volatile("s_waitcnt vmcnt(0) lgkmcnt(0)" ::: "memory");
    __builtin_amdgcn_s_barrier();
  };

  // prologue: stage+gen step 0
  STAGEB(LB0, 0);
  GENA(LA0, 0);
  asm volatile("s_waitcnt vmcnt(0) lgkmcnt(0)" ::: "memory");
  __builtin_amdgcn_s_barrier();

  for (int s2 = 0; s2 < NST; s2 += 2){
    STEP(LB0, LA0, LB1, LA1, s2);
    STEP(LB1, LA1, LB0, LA0, s2 + 1);
  }

  // ---- row sums -> softmax denom. thread's rows were fixed: row = t>>4,
  // i.e. lanes [16q,16q+16) of wave w hold partials of local row 4w+q.
  float v = myS;
  v += __shfl_down(v, 8, 16);
  v += __shfl_down(v, 4, 16);
  v += __shfl_down(v, 2, 16);
  v += __shfl_down(v, 1, 16);
  float* Ssum = reinterpret_cast<float*>(sm);   // LDS free now (reuse Bs0)
  if (l15 == 0) Ssum[w * 4 + lq] = v;
  __syncthreads();

  float rinv[4];
  #pragma unroll
  for (int r = 0; r < 4; ++r)
    rinv[r] = 1.0f / Ssum[wr + lq * 4 + r];

  #pragma unroll
  for (int n = 0; n < 16; ++n){
    const size_t col = (size_t)wn0 + n * 16 + l15;
    #pragma unroll
    for (int r = 0; r < 4; ++r){
      const size_t row = m0 + wr + lq * 4 + r;  // C/D: col=lane&15, row=quad*4+reg
      __builtin_nontemporal_store(acc[n][r] * rinv[r], &O[row * DDIM + col]);
    }
  }
}

// ---------------------------------------------------------------------------
extern "C" void kernel_launch(void* const* d_in, const int* in_sizes, int n_in,
                              void* d_out, int out_size, void* d_ws, size_t ws_size,
                              hipStream_t stream)
{
  (void)in_sizes; (void)n_in; (void)out_size;
  const float* x = (const float*)d_in[0];       // [8192][1024] f32; d_in[1] unused
  float* O = (float*)d_out;                     // [8192][1024] f32
  uint8_t* ws = (uint8_t*)d_ws;

  // workspace: only xT (16.8 MB) -- P is never materialized.
  uint16_t* xT = (uint16_t*)ws;
  const size_t xT_bytes = (size_t)DDIM * NROWS * sizeof(uint16_t);
  if (ws_size < xT_bytes) return;               // cannot run without xT staging

  transpose_cast<<<dim3(DDIM/32, NROWS/32), 256, 0, stream>>>(x, xT);
  fused32<<<256, 512, LDS_ELEMS * sizeof(uint16_t), stream>>>(xT, O);
}

// Round 5
// 410.422 us; speedup vs baseline: 1.1686x; 1.1686x over previous
//
#include <hip/hip_runtime.h>
#include <stdint.h>
#include <stddef.h>

#define NROWS 8192
#define NCOLS 8192       // K dimension = noise-matrix column count
#define DDIM  1024

typedef float  f32x4 __attribute__((ext_vector_type(4)));
typedef _Float16 f16x8 __attribute__((ext_vector_type(8)));

#if __has_builtin(__builtin_amdgcn_exp2f)
#define EXP2F(x) __builtin_amdgcn_exp2f(x)
#else
#define EXP2F(x) exp2f(x)
#endif
#if __has_builtin(__builtin_amdgcn_logf)
#define LOG2F(x) __builtin_amdgcn_logf(x)     // v_log_f32 = log2
#else
#define LOG2F(x) log2f(x)
#endif
#if __has_builtin(__builtin_amdgcn_sqrtf)
#define SQRTF(x) __builtin_amdgcn_sqrtf(x)
#else
#define SQRTF(x) sqrtf(x)
#endif

// ---------------- Threefry-2x32, key = (0, 42) (jax.random.key(42)) ---------
__device__ __forceinline__ uint32_t rotl32(uint32_t x, uint32_t r){
  return (x << r) | (x >> (32u - r));
}

__device__ __forceinline__ void threefry2x32(uint32_t x0, uint32_t x1,
                                             uint32_t& o0, uint32_t& o1){
  const uint32_t k0 = 0u, k1 = 42u;
  const uint32_t k2 = k0 ^ k1 ^ 0x1BD11BDAu;
  x0 += k0; x1 += k1;
#define TF_R(r) { x0 += x1; x1 = rotl32(x1, r); x1 ^= x0; }
  TF_R(13) TF_R(15) TF_R(26) TF_R(6)
  x0 += k1; x1 += k2 + 1u;
  TF_R(17) TF_R(29) TF_R(16) TF_R(24)
  x0 += k2; x1 += k0 + 2u;
  TF_R(13) TF_R(15) TF_R(26) TF_R(6)
  x0 += k0; x1 += k1 + 3u;
  TF_R(17) TF_R(29) TF_R(16) TF_R(24)
  x0 += k1; x1 += k2 + 4u;
  TF_R(13) TF_R(15) TF_R(26) TF_R(6)
  x0 += k2; x1 += k0 + 5u;
#undef TF_R
  o0 = x0; o1 = x1;
}

// Partitionable-threefry element: flat index f -> E' = exp(2*normal)*2^-4.
__device__ __forceinline__ float elemE(uint32_t f){
  uint32_t o0, o1;
  threefry2x32(0u, f, o0, o1);
  const uint32_t b = o0 ^ o1;
  float u = __uint_as_float((b >> 9) | 0x3F800000u) - 1.0f;   // [0,1)
  const float lo = -0.99999994f;                              // nextafter(-1,0)
  float v = fmaf(u, 2.0f, lo);
  v = fmaxf(v, lo);
  const float t1 = fmaf(-v, v, 1.0f);                         // 1 - v^2
  float w = LOG2F(t1) * (-0.69314718f);                       // -ln(1-v^2)
  float p;
  if (w < 5.0f){
    w -= 2.5f;
    p =              3.97426473e-08f;
    p = fmaf(p, w,   4.85465e-07f);
    p = fmaf(p, w,  -4.98283e-06f);
    p = fmaf(p, w,  -6.21053e-06f);
    p = fmaf(p, w,   3.09120e-04f);
    p = fmaf(p, w,  -1.77290e-03f);
    p = fmaf(p, w,  -5.90817e-03f);
    p = fmaf(p, w,   3.48803163e-01f);
    p = fmaf(p, w,   2.12331355e+00f);
  } else {
    w = SQRTF(w) - 3.0f;
    p =             -2.83147363e-04f;
    p = fmaf(p, w,   1.42765560e-04f);
    p = fmaf(p, w,   1.90825981e-03f);
    p = fmaf(p, w,  -5.19500608e-03f);
    p = fmaf(p, w,   8.11688602e-03f);
    p = fmaf(p, w,  -1.07798386e-02f);
    p = fmaf(p, w,   1.33487061e-02f);
    p = fmaf(p, w,   1.41658096e+00f);
    p = fmaf(p, w,   4.00643396e+00f);
  }
  const float m = p * v;                         // sqrt(2)*erfinv(v) ~ N(0,1)
  return EXP2F(fmaf(m, 2.8853900817779268f, -4.0f)); // exp(2m)*2^-4
}

__device__ __forceinline__ uint16_t f2h(float a){
  union { _Float16 h; uint16_t u; } c; c.h = (_Float16)a; return c.u;
}

// ---------------- transpose: x [8192][1024] f32 -> xT f16 -------------------
__global__ __launch_bounds__(256) void transpose_cast(const float* __restrict__ x,
                                                      uint16_t* __restrict__ xT){
  __shared__ float tile[32][33];
  const int tx = threadIdx.x & 31;
  const int ty = threadIdx.x >> 5;          // 0..7
  const int dcol = blockIdx.x * 32;
  const int nrow = blockIdx.y * 32;
  #pragma unroll
  for (int r = 0; r < 32; r += 8)
    tile[ty + r][tx] = x[(size_t)(nrow + ty + r) * DDIM + dcol + tx];
  __syncthreads();
  #pragma unroll
  for (int r = 0; r < 32; r += 8)
    xT[(size_t)(dcol + ty + r) * NROWS + nrow + tx] = f2h(tile[tx][ty + r]);
}

typedef const __attribute__((address_space(1))) void GAS;
typedef __attribute__((address_space(3))) void LAS;

__device__ __forceinline__ void gload16(const void* g, void* l){
  __builtin_amdgcn_global_load_lds((GAS*)g, (LAS*)l, 16, 0, 0);
}

// ============= fused generate-in-GEMM v2 (no P materialization) =============
// Grid = 256 blocks x 1024 threads (16 waves, 4/SIMD), 1 block/CU (132 KB
// LDS). Block b owns output rows [32b,32b+32) x all 1024 cols; streams K in
// 256 steps of 32. Per step: generates its 32x32 A-tile into LDS (1 elemE
// per thread -- P never touches memory), stages the 1024x32 xT K-slice via
// global_load_lds. Wave w computes the 64-col stripe [64w,64w+64): LDS bytes
// per step = A 32KB + B 64KB read + 68KB written (minimum for LDS-staged B).
//
// LDS swizzle (round-4 fix: 35.6M bank conflicts -> ~0): rows paired into
// 128-byte superrows (32 banks, no row aliasing). 8 slots of 16B per
// superrow; logical granule g of row d: g3 = g | ((d&1)<<2), phys slot
// p = g3 ^ (sr&7) (XOR involution). Verified: every frag-read quarter-wave
// lands exactly 2 lanes per bank-group = 2-way = free (m136). Staging keeps
// a LINEAR LDS dest and inverse-swizzles the GLOBAL source (rule 21).
//
// LDS byte map: A0 @0 (2KB) | A1 @2048 | B0 @4096 (64KB) | B1 @69632.
#define FM2 32
#define FK2 32
#define NST (NCOLS / FK2)    // 256 K-steps
#define A0_OFF 0
#define A1_OFF 2048
#define B0_OFF 4096
#define B1_OFF 69632
#define LDS_BYTES 135168

__global__ __launch_bounds__(1024, 4) void fused32v2(
    const uint16_t* __restrict__ xT,   // [1024][8192] f16
    float* __restrict__ O)             // [8192][1024] f32
{
  extern __shared__ uint8_t smb[];

  const int t = threadIdx.x;
  const size_t m0 = (size_t)blockIdx.x * FM2;

  const int lane = t & 63;
  const int w    = t >> 6;             // 0..15; wave covers cols [64w, 64w+64)
  const int l15  = lane & 15;
  const int lq   = lane >> 4;          // 0..3 = k-granule of the MFMA frag

  // ---- gen mapping: thread t -> (row t>>5, k-col t&31), 1 element/step ----
  const int grow = t >> 5;             // 0..31
  const int gcol = t & 31;
  const uint32_t genbase = (uint32_t)(m0 + (size_t)grow) * 8192u + (uint32_t)gcol;
  const int a_sr = grow >> 1;
  const int a_g3 = (gcol >> 3) | ((grow & 1) << 2);
  const int aw_off = a_sr * 128 + (a_g3 ^ (a_sr & 7)) * 16 + (gcol & 7) * 2;

  // ---- B staging: 4096 granules/step; thread t covers lin = t + 1024r.
  // lin -> sr=lin>>3, p=lin&7; logical g3 = p ^ (sr&7) (const in r since
  // 128r = 0 mod 8); d = (sr<<1)|(g3>>2) = d0 + 256r; k-granule = g3&3.
  const int s_g3 = (t & 7) ^ ((t >> 3) & 7);
  const int s_d0 = (((t >> 3) << 1) | (s_g3 >> 2));
  const uint16_t* gB = xT + (size_t)s_d0 * NCOLS + (s_g3 & 3) * 8;

  // ---- frag-read byte offsets (within a buffer) ----
  // phys slot p = (lq | ((row&1)<<2)) ^ ((row>>1)&7): 2 lanes/bank-group.
  const int fp = (lq | ((l15 & 1) << 2)) ^ ((l15 >> 1) & 7);
  int af_off[2];
  #pragma unroll
  for (int i = 0; i < 2; ++i)
    af_off[i] = (i * 8 + (l15 >> 1)) * 128 + fp * 16;
  int bf_off[4];
  #pragma unroll
  for (int f = 0; f < 4; ++f)
    bf_off[f] = (w * 32 + f * 8 + (l15 >> 1)) * 128 + fp * 16;

  float myS = 0.0f;
  f32x4 acc[2][4];
  #pragma unroll
  for (int i = 0; i < 2; ++i)
    #pragma unroll
    for (int f = 0; f < 4; ++f)
      #pragma unroll
      for (int r = 0; r < 4; ++r) acc[i][f][r] = 0.0f;

  auto STAGEB = [&](int bbuf, int s){
    const int k0 = s * FK2;
    #pragma unroll
    for (int r = 0; r < 4; ++r)
      gload16(gB + (size_t)(256 * r) * NCOLS + k0,
              smb + bbuf + (t + 1024 * r) * 16);
  };
  auto GENA = [&](int abuf, int s){
    const float e = elemE(genbase + (uint32_t)(s * FK2));
    myS += e;
    *reinterpret_cast<_Float16*>(smb + abuf + aw_off) = (_Float16)e;
  };
  auto STEP = [&](int ca, int cb, int na, int nb, int s){
    if (s + 1 < NST){
      STAGEB(nb, s + 1);               // VMEM, in flight across the step
      GENA(na, s + 1);                 // ~95 VALU insts: hides latency
    }
    f16x8 af[2], bf[4];
    #pragma unroll
    for (int i = 0; i < 2; ++i)
      af[i] = *reinterpret_cast<const f16x8*>(smb + ca + af_off[i]);
    #pragma unroll
    for (int f = 0; f < 4; ++f)
      bf[f] = *reinterpret_cast<const f16x8*>(smb + cb + bf_off[f]);
    __builtin_amdgcn_s_setprio(1);
    #pragma unroll
    for (int i = 0; i < 2; ++i)
      #pragma unroll
      for (int f = 0; f < 4; ++f)
        acc[i][f] = __builtin_amdgcn_mfma_f32_16x16x32_f16(af[i], bf[f], acc[i][f], 0, 0, 0);
    __builtin_amdgcn_s_setprio(0);
    // drain staging loads (issued at step start, ~4 waves/SIMD of VALU ago)
    // + gen writes + frag reads; then barrier -> next buffers valid.
    asm volatile("s_waitcnt vmcnt(0) lgkmcnt(0)" ::: "memory");
    __builtin_amdgcn_s_barrier();
  };

  // prologue: stage+gen step 0
  STAGEB(B0_OFF, 0);
  GENA(A0_OFF, 0);
  asm volatile("s_waitcnt vmcnt(0) lgkmcnt(0)" ::: "memory");
  __builtin_amdgcn_s_barrier();

  for (int s = 0; s < NST; s += 2){
    STEP(A0_OFF, B0_OFF, A1_OFF, B1_OFF, s);
    STEP(A1_OFF, B1_OFF, A0_OFF, B0_OFF, s + 1);
  }

  // ---- row sums -> softmax denominators. Lanes [0..31]/[32..63] of wave w
  // hold partials of rows 2w / 2w+1 (row = t>>5). Reduce within 32 lanes.
  float v = myS;
  v += __shfl_down(v, 16, 32);
  v += __shfl_down(v, 8, 32);
  v += __shfl_down(v, 4, 32);
  v += __shfl_down(v, 2, 32);
  v += __shfl_down(v, 1, 32);
  float* Ssum = reinterpret_cast<float*>(smb);   // buffers dead; reuse
  if ((lane & 31) == 0) Ssum[t >> 5] = v;
  __syncthreads();

  float rinv[2][4];
  #pragma unroll
  for (int i = 0; i < 2; ++i)
    #pragma unroll
    for (int r = 0; r < 4; ++r)
      rinv[i][r] = 1.0f / Ssum[i * 16 + lq * 4 + r];
  __syncthreads();   // all reads done before any (hypothetical) reuse

  #pragma unroll
  for (int i = 0; i < 2; ++i)
    #pragma unroll
    for (int f = 0; f < 4; ++f){
      const size_t col = (size_t)w * 64 + f * 16 + l15;
      #pragma unroll
      for (int r = 0; r < 4; ++r){
        const size_t row = m0 + i * 16 + lq * 4 + r;  // C/D: col=lane&15, row=quad*4+reg
        __builtin_nontemporal_store(acc[i][f][r] * rinv[i][r], &O[row * DDIM + col]);
      }
    }
}

// ---------------------------------------------------------------------------
extern "C" void kernel_launch(void* const* d_in, const int* in_sizes, int n_in,
                              void* d_out, int out_size, void* d_ws, size_t ws_size,
                              hipStream_t stream)
{
  (void)in_sizes; (void)n_in; (void)out_size;
  const float* x = (const float*)d_in[0];       // [8192][1024] f32; d_in[1] unused
  float* O = (float*)d_out;                     // [8192][1024] f32
  uint8_t* ws = (uint8_t*)d_ws;

  // workspace: only xT (16.8 MB) -- P is never materialized.
  uint16_t* xT = (uint16_t*)ws;
  const size_t xT_bytes = (size_t)DDIM * NROWS * sizeof(uint16_t);
  if (ws_size < xT_bytes) return;               // cannot run without xT staging

  transpose_cast<<<dim3(DDIM/32, NROWS/32), 256, 0, stream>>>(x, xT);
  fused32v2<<<256, 1024, LDS_BYTES, stream>>>(xT, O);
}